// Round 9
// baseline (1649.193 us; speedup 1.0000x reference)
//
#include <hip/hip_runtime.h>
#include <hip/hip_bf16.h>
#include <hip/hip_cooperative_groups.h>

namespace cg = cooperative_groups;

// Sizes
#define B_ 256
#define D_ 3072
#define H_ 256
#define OPT_ 32
#define OD_ 98304       // OPT_*D_
#define NL_ 4

typedef __attribute__((ext_vector_type(8))) short short8;
typedef __attribute__((ext_vector_type(4))) float f32x4;

__device__ __forceinline__ unsigned short f2bf(float f) {
    unsigned int u = __float_as_uint(f);
    unsigned int r = (u + 0x7FFFu + ((u >> 16) & 1u)) >> 16;
    return (unsigned short)r;
}

// ---------------------------------------------------------------------------
// MEGA: whole encoder in ONE cooperative kernel. Grid 512 x 512 = 2 blocks/CU
// (LDS 60KB, VGPR capped 128 by launch_bounds) -> co-residency guaranteed.
// R8 probe: g2 standalone = 43 us/launch (fill ~11 + 1.5-wave tail); 24
// launches/iter paid fill+gap each. Fusion fills the machine ONCE and
// load-balances g2's 768 tiles via an atomic ticket (order-independent:
// tile outputs are disjoint).
__global__ __launch_bounds__(512, 4) void mega_kernel(
    const float* __restrict__ x,    // [256][3072]
    const float* __restrict__ Wb,   // [3072][256]
    const float* __restrict__ bb,   // [256]
    const float* __restrict__ Wo,   // [4][256][98304]
    const float* __restrict__ bo,   // [4][98304]
    const float* __restrict__ bias, // [4][32][3072]
    float* __restrict__ enc,        // [256][4]
    float* __restrict__ cur,        // [256][3072]
    float* __restrict__ zpart,      // [16][256][256]
    float* __restrict__ partial,    // [256][32][48]
    float* __restrict__ rx,         // [256][3072]
    float* __restrict__ basef,      // [256][256]
    unsigned char* __restrict__ base_ready,  // 163840 B
    int* __restrict__ idxbuf,       // [256]
    int* __restrict__ g2tk)         // [4] tickets
{
    cg::grid_group grid = cg::this_grid();
    __shared__ __align__(16) unsigned char lds[61440];
    __shared__ int s_next;

    const int t = threadIdx.x;
    const int blk = blockIdx.x;     // 0..511

    // ---- INIT: cur=0, rx=-x, zpart=0, tickets=512 ----
    {
        int gid0 = blk * 512 + t;   // 262144 threads
        for (int g = gid0; g < B_ * D_; g += 262144) {
            cur[g] = 0.f;
            rx[g] = -x[g];
        }
        for (int g = gid0; g < 16 * B_ * H_; g += 262144) zpart[g] = 0.f;
        if (gid0 < NL_) g2tk[gid0] = 512;
    }
    grid.sync();

    const int lane = t & 63, wv = t >> 6;
    const int wm = wv >> 1, wn = wv & 1;
    const int lrow = lane & 15, lk = lane >> 4;
    const int nW = t & 127, kq = t >> 7;

    for (int i = 0; i < NL_; ++i) {
        const float* WoL   = Wo + (size_t)i * H_ * OD_;
        const float* boLp  = bo + (size_t)i * OD_;
        const float* biasL = bias + (size_t)i * OD_;

        // ---- GEMM1 (layers 1-3): zpart[ks][b][h], bitwise-same k-order ----
        if (i > 0) {
            int ks = blk >> 5, bg = blk & 31;
            int half = t >> 8, h = t & 255;
            const float* wp = Wb + (size_t)ks * 192 * H_ + h;
            const float* cp = cur + (size_t)(bg * 8 + half * 4) * D_ + ks * 192;
            float acc1[4] = {0.f, 0.f, 0.f, 0.f};
#pragma unroll 4
            for (int dd = 0; dd < 192; ++dd) {
                float w = wp[(size_t)dd * H_];
#pragma unroll
                for (int g = 0; g < 4; ++g) acc1[g] += cp[(size_t)g * D_ + dd] * w;
            }
#pragma unroll
            for (int g = 0; g < 4; ++g)
                zpart[ks * (B_ * H_) + (bg * 8 + half * 4 + g) * H_ + h] = acc1[g];
            grid.sync();
        }

        // ---- E: base = relu(sum zpart + bb) -> bf16 image + f32 basef ----
        if (blk < 256 && t < 256) {
            int m = blk, k = t;
            float z = bb[k];
#pragma unroll
            for (int ks = 0; ks < 16; ++ks) z += zpart[ks * (B_ * H_) + m * H_ + k];
            z = z > 0.f ? z : 0.f;
            *(unsigned short*)(base_ready + (k >> 5) * 20480 + m * 80 + (k & 31) * 2) = f2bf(z);
            basef[m * H_ + k] = z;
        }
        grid.sync();

        // ---- G2: ticket loop over 768 tiles (R7 body, bx -> tile) ----
        {
            unsigned char* ldsA = lds;            // [2][20480]
            unsigned char* ldsW = lds + 40960;    // [2][10240]

#define DMA_A(S, BUF) {                                                                  \
    const unsigned char* gA = base_ready + (S) * 20480;                                  \
    __builtin_amdgcn_global_load_lds(                                                    \
        (const __attribute__((address_space(1))) unsigned int*)(gA + t * 16),            \
        (__attribute__((address_space(3))) unsigned int*)(ldsA + (BUF) * 20480 + wv * 1024), \
        16, 0, 0);                                                                       \
    __builtin_amdgcn_global_load_lds(                                                    \
        (const __attribute__((address_space(1))) unsigned int*)(gA + 8192 + t * 16),     \
        (__attribute__((address_space(3))) unsigned int*)(ldsA + (BUF) * 20480 + 8192 + wv * 1024), \
        16, 0, 0);                                                                       \
    if (wv < 4)                                                                          \
        __builtin_amdgcn_global_load_lds(                                                \
            (const __attribute__((address_space(1))) unsigned int*)(gA + 16384 + t * 16),\
            (__attribute__((address_space(3))) unsigned int*)(ldsA + (BUF) * 20480 + 16384 + wv * 1024), \
            16, 0, 0); }

#define LOADW_(S, WF) {                                                                  \
    const float* gp0 = WoL + (size_t)((S) * 32 + kq * 4) * OD_ + ncol0 + nW;             \
    WF[0] = gp0[0]; WF[1] = gp0[OD_]; WF[2] = gp0[2 * OD_]; WF[3] = gp0[3 * OD_];        \
    const float* gp1 = gp0 + (size_t)16 * OD_;                                           \
    WF[4] = gp1[0]; WF[5] = gp1[OD_]; WF[6] = gp1[2 * OD_]; WF[7] = gp1[3 * OD_]; }

#define WRITEW_(BUF, WF) {                                                               \
    uint2 pk0, pk1;                                                                      \
    pk0.x = (unsigned)f2bf(WF[0]) | ((unsigned)f2bf(WF[1]) << 16);                       \
    pk0.y = (unsigned)f2bf(WF[2]) | ((unsigned)f2bf(WF[3]) << 16);                       \
    *(uint2*)(ldsW + (BUF) * 10240 + nW * 80 + kq * 8) = pk0;                            \
    pk1.x = (unsigned)f2bf(WF[4]) | ((unsigned)f2bf(WF[5]) << 16);                       \
    pk1.y = (unsigned)f2bf(WF[6]) | ((unsigned)f2bf(WF[7]) << 16);                       \
    *(uint2*)(ldsW + (BUF) * 10240 + nW * 80 + 32 + kq * 8) = pk1; }

            int tile = blk;
            while (tile < 768) {
                int ncol0 = tile * 128;
                int o = tile / 24;
                int dbase = (tile % 24) * 128;

                f32x4 acc[4][4];
#pragma unroll
                for (int mi = 0; mi < 4; ++mi)
#pragma unroll
                    for (int ni = 0; ni < 4; ++ni) acc[mi][ni] = 0.f;

                float wfX[8], wfY[8];

                DMA_A(0, 0);
                LOADW_(0, wfX);
                LOADW_(1, wfY);
                WRITEW_(0, wfX);
                asm volatile("s_waitcnt lgkmcnt(0)" ::: "memory");
                __builtin_amdgcn_s_barrier();

#pragma unroll 2
                for (int s = 0; s < 8; ++s) {
                    int pb = s & 1;
                    if (s < 7) DMA_A(s + 1, pb ^ 1);
                    if (s < 6) {
                        if ((s & 1) == 0) { LOADW_(s + 2, wfX); }
                        else              { LOADW_(s + 2, wfY); }
                    }
                    short8 bfr[4];
#pragma unroll
                    for (int ni = 0; ni < 4; ++ni) {
                        int nn = wn * 64 + ni * 16 + lrow;
                        bfr[ni] = *(const short8*)(ldsW + pb * 10240 + nn * 80 + lk * 16);
                    }
#pragma unroll
                    for (int mi = 0; mi < 4; ++mi) {
                        int row = wm * 64 + mi * 16 + lrow;
                        short8 af = *(const short8*)(ldsA + pb * 20480 + row * 80 + lk * 16);
#pragma unroll
                        for (int ni = 0; ni < 4; ++ni)
                            acc[mi][ni] = __builtin_amdgcn_mfma_f32_16x16x32_bf16(af, bfr[ni], acc[mi][ni], 0, 0, 0);
                    }
                    if (s < 7) {
                        if ((s & 1) == 0) { WRITEW_(pb ^ 1, wfY); }
                        else              { WRITEW_(pb ^ 1, wfX); }
                        if (s < 6) asm volatile("s_waitcnt vmcnt(8) lgkmcnt(0)" ::: "memory");
                        else       asm volatile("s_waitcnt vmcnt(0) lgkmcnt(0)" ::: "memory");
                        __builtin_amdgcn_s_barrier();
                    }
                }

                // epilogue: loss partials
                float q[4];
#pragma unroll
                for (int ni = 0; ni < 4; ++ni) {
                    int dcol = dbase + wn * 64 + ni * 16 + lrow;
                    q[ni] = biasL[o * D_ + dcol] + boLp[o * D_ + dcol];
                }
                float ssum[4][4];
#pragma unroll
                for (int mi = 0; mi < 4; ++mi)
#pragma unroll
                    for (int r = 0; r < 4; ++r) ssum[mi][r] = 0.f;
#pragma unroll
                for (int mi = 0; mi < 4; ++mi) {
#pragma unroll
                    for (int ni = 0; ni < 4; ++ni) {
                        int dcol = dbase + wn * 64 + ni * 16 + lrow;
#pragma unroll
                        for (int r = 0; r < 4; ++r) {
                            int rowm = wm * 64 + mi * 16 + lk * 4 + r;
                            float tv = acc[mi][ni][r] + rx[rowm * D_ + dcol] + q[ni];
                            ssum[mi][r] += tv * tv;
                        }
                    }
                }
#pragma unroll
                for (int mi = 0; mi < 4; ++mi)
#pragma unroll
                    for (int r = 0; r < 4; ++r) {
                        float v = ssum[mi][r];
                        v += __shfl_xor(v, 1);
                        v += __shfl_xor(v, 2);
                        v += __shfl_xor(v, 4);
                        v += __shfl_xor(v, 8);
                        if (lrow == 0) {
                            int rowm = wm * 64 + mi * 16 + lk * 4 + r;
                            partial[(rowm * OPT_ + o) * 48 + (tile % 24) * 2 + wn] = v;
                        }
                    }

                __syncthreads();
                if (t == 0) s_next = atomicAdd(&g2tk[i], 1);
                __syncthreads();
                tile = s_next;
            }
#undef DMA_A
#undef LOADW_
#undef WRITEW_
        }
        grid.sync();

        // ---- C: per-b argmin (tie-break lowest index) ----
        if (blk < 256) {
            float* ls = (float*)lds;
            if (t < 256) {
                int oo = t >> 3, j8 = t & 7;
                const float* pp = partial + (blk * OPT_ + oo) * 48;
                float v = 0.f;
#pragma unroll
                for (int j = 0; j < 6; ++j) v += pp[j8 + 8 * j];
                v += __shfl_xor(v, 1);
                v += __shfl_xor(v, 2);
                v += __shfl_xor(v, 4);
                if (j8 == 0) ls[oo] = v;
            }
            __syncthreads();
            if (t < 32) {
                float mv = ls[t];
                int mi = t;
#pragma unroll
                for (int m = 16; m >= 1; m >>= 1) {
                    float ov = __shfl_xor(mv, m);
                    int oi = __shfl_xor(mi, m);
                    if (ov < mv || (ov == mv && oi < mi)) { mv = ov; mi = oi; }
                }
                if (t == 0) {
                    idxbuf[blk] = mi;
                    enc[blk * NL_ + i] = (float)mi;
                }
            }
        }
        grid.sync();

        // ---- D: bucketed recompute (rank-scan, no atomics) ----
        {
            int* sidx    = (int*)lds;              // 256 ints
            int* scnt    = (int*)(lds + 1024);     // 32
            int* snch    = (int*)(lds + 1152);     // 32
            int* chunk_b = (int*)(lds + 1280);     // 8
            float (*basL)[256] = (float(*)[256])(lds + 1344);  // 8x256 f32

            if (t < 256) sidx[t] = idxbuf[t];
            __syncthreads();
            if (t < 32) {
                int c = 0;
                for (int b2 = 0; b2 < 256; ++b2) c += (sidx[b2] == t);
                scnt[t] = c;
                snch[t] = (c + 7) >> 3;
            }
            __syncthreads();
            int nitems = 0;
            for (int oo = 0; oo < 32; ++oo) nitems += snch[oo];
            int myo = -1, myrank = 0;
            if (t < 256) {
                myo = sidx[t];
                for (int b2 = 0; b2 < t; ++b2) myrank += (sidx[b2] == myo);
            }
            if (blk < 384) {
                int dtpair = blk >> 6, j = blk & 63;
                if (j < nitems) {
                    int o = 0, ch = 0, pre = 0;
                    for (int oo = 0; oo < 32; ++oo) {
                        int n = snch[oo];
                        if (j < pre + n) { o = oo; ch = j - pre; break; }
                        pre += n;
                    }
                    int cnt = scnt[o];
                    int c0 = ch * 8;
                    int rem = cnt - c0;
                    if (rem > 8) rem = 8;
                    if (t < 256 && myo == o && myrank >= c0 && myrank < c0 + 8)
                        chunk_b[myrank - c0] = t;
                    __syncthreads();
                    int bidx[8];
#pragma unroll
                    for (int g = 0; g < 8; ++g) bidx[g] = chunk_b[(g < rem) ? g : (rem - 1)];
                    // stage basL: static g indices (rule #20), 512 threads
                    {
                        int col = t & 255, gh = t >> 8;
#pragma unroll
                        for (int qd = 0; qd < 4; ++qd)
                            basL[qd * 2 + gh][col] = basef[chunk_b[(qd * 2 + gh) < rem ? (qd * 2 + gh) : (rem - 1)] * H_ + col];
                    }
                    __syncthreads();
                    int dt = dtpair * 2 + (t >> 8);
                    int d = dt * 256 + (t & 255);
                    const float* wp = WoL + (size_t)o * D_ + d;
                    size_t nn2 = (size_t)o * D_ + d;
                    float bov = boLp[nn2];
                    float biv = biasL[nn2];
                    float acc2[8] = {0.f, 0.f, 0.f, 0.f, 0.f, 0.f, 0.f, 0.f};
                    for (int k0 = 0; k0 < 256; k0 += 8) {
                        float w[8];
#pragma unroll
                        for (int u = 0; u < 8; ++u) w[u] = wp[(size_t)(k0 + u) * OD_];
#pragma unroll
                        for (int h2 = 0; h2 < 2; ++h2) {
                            int kb = k0 + h2 * 4;
                            f32x4 bv[8];
#pragma unroll
                            for (int g = 0; g < 8; ++g) bv[g] = *(const f32x4*)&basL[g][kb];
#pragma unroll
                            for (int u = 0; u < 4; ++u) {
                                float wu = w[h2 * 4 + u];
#pragma unroll
                                for (int g = 0; g < 8; ++g) acc2[g] += bv[g][u] * wu;   // k ascending
                            }
                        }
                    }
#pragma unroll
                    for (int g = 0; g < 8; ++g) {
                        if (g < rem) {
                            int b_ex = bidx[g];
                            float outv = cur[b_ex * D_ + d] + acc2[g] + bov + biv;
                            cur[b_ex * D_ + d] = outv;
                            rx[b_ex * D_ + d] = outv - x[b_ex * D_ + d];
                        }
                    }
                }
            }
        }
        grid.sync();
    }
}

// ---------------------------------------------------------------------------
extern "C" void kernel_launch(void* const* d_in, const int* in_sizes, int n_in,
                              void* d_out, int out_size, void* d_ws, size_t ws_size,
                              hipStream_t stream) {
    const float* x    = (const float*)d_in[0];
    const float* Wb   = (const float*)d_in[1];
    const float* bb   = (const float*)d_in[2];
    const float* Wo   = (const float*)d_in[3];
    const float* bo   = (const float*)d_in[4];
    const float* bias = (const float*)d_in[5];

    float* out = (float*)d_out;
    float* enc = out;            // [256][4]
    float* cur = out + 1024;     // [256][3072]

    float* ws = (float*)d_ws;
    float* zpart   = ws;                          // 16*256*256 = 1048576
    float* partial = ws + 1048576;                // 256*32*48  = 393216
    float* rx      = ws + 1441792;                // 256*3072   = 786432
    float* basef   = ws + 2228224;                // 256*256    = 65536
    unsigned char* base_ready = (unsigned char*)(ws + 2293760);  // 163840 B
    int* idxbuf    = (int*)(ws + 2334720);        // 256 ints
    int* g2tk      = (int*)(ws + 2334976);        // 4 ints

    void* args[] = {
        (void*)&x, (void*)&Wb, (void*)&bb, (void*)&Wo, (void*)&bo, (void*)&bias,
        (void*)&enc, (void*)&cur, (void*)&zpart, (void*)&partial, (void*)&rx,
        (void*)&basef, (void*)&base_ready, (void*)&idxbuf, (void*)&g2tk
    };
    hipLaunchCooperativeKernel(mega_kernel, dim3(512), dim3(512), args, 0, stream);
}

// Round 10
// 500.426 us; speedup vs baseline: 3.2956x; 3.2956x over previous
//
#include <hip/hip_runtime.h>
#include <hip/hip_bf16.h>

// Sizes
#define B_ 256
#define D_ 3072
#define H_ 256
#define OPT_ 32
#define OD_ 98304       // OPT_*D_
#define NL_ 4

typedef __attribute__((ext_vector_type(8))) short short8;
typedef __attribute__((ext_vector_type(4))) float f32x4;

__device__ __forceinline__ unsigned short f2bf(float f) {
    unsigned int u = __float_as_uint(f);
    unsigned int r = (u + 0x7FFFu + ((u >> 16) & 1u)) >> 16;
    return (unsigned short)r;
}

// ---------------------------------------------------------------------------
// init: cur=0, rx=-x, zpart=0, g2 tickets. 256 blocks (ramp ~5.6us), stride.
__global__ __launch_bounds__(256) void init_kernel(const float* __restrict__ x,
                                                   float* __restrict__ cur,
                                                   float* __restrict__ rx,
                                                   float* __restrict__ zpart,
                                                   int* __restrict__ g2tk) {
    int gid0 = blockIdx.x * 256 + threadIdx.x;   // 65536 threads
    for (int g = gid0; g < B_ * D_; g += 65536) {
        cur[g] = 0.f;
        rx[g] = -x[g];
    }
    for (int g = gid0; g < 8 * B_ * H_; g += 65536) zpart[g] = 0.f;
    if (gid0 < NL_) g2tk[gid0] = 512;
}

// ---------------------------------------------------------------------------
// gemm1: zpart[ks][b][h] = sum_{d in 384-slice ks} cur[b][d] * Wb[d][h]
// 256 blocks (8 kslices x 32 bgroups of 8 b; ramp ~5.6us), 256 threads (= h).
// cur reads wave-uniform (scalar pipe), Wb coalesced.
__global__ __launch_bounds__(256) void gemm1_kernel(const float* __restrict__ cur,
                                                    const float* __restrict__ Wb,
                                                    float* __restrict__ zpart) {
    int t = threadIdx.x;
    int ks = blockIdx.x >> 5;     // 0..7
    int bg = blockIdx.x & 31;     // 0..31
    const float* wp = Wb + (size_t)ks * 384 * H_ + t;
    const float* cp = cur + (size_t)(bg * 8) * D_ + ks * 384;
    float acc[8] = {0.f, 0.f, 0.f, 0.f, 0.f, 0.f, 0.f, 0.f};
#pragma unroll 4
    for (int dd = 0; dd < 384; ++dd) {
        float w = wp[(size_t)dd * H_];
#pragma unroll
        for (int g = 0; g < 8; ++g) acc[g] += cp[(size_t)g * D_ + dd] * w;
    }
#pragma unroll
    for (int g = 0; g < 8; ++g)
        zpart[ks * (B_ * H_) + (bg * 8 + g) * H_ + t] = acc[g];
}

// ---------------------------------------------------------------------------
// E: base = relu(sum_ks zpart + bb) -> bf16 image + f32 basef.
// 64 blocks x 4 rows each (ramp ~1.4us).
__global__ __launch_bounds__(256) void e_kernel(const float* __restrict__ zpart,
                                                const float* __restrict__ bb,
                                                unsigned char* __restrict__ base_ready,
                                                float* __restrict__ basef) {
    int k = threadIdx.x;
    float bbk = bb[k];
#pragma unroll
    for (int mm = 0; mm < 4; ++mm) {
        int m = blockIdx.x * 4 + mm;
        float z = bbk;
#pragma unroll
        for (int ks = 0; ks < 8; ++ks) z += zpart[ks * (B_ * H_) + m * H_ + k];
        z = z > 0.f ? z : 0.f;
        *(unsigned short*)(base_ready + (k >> 5) * 20480 + m * 80 + (k & 31) * 2) = f2bf(z);
        basef[m * H_ + k] = z;
    }
}

// ---------------------------------------------------------------------------
// G2: fused GEMM (256x98304, K=256, bf16 MFMA) + squared-loss partials.
// R7 body (counted-vmcnt schedule). Grid 512 (ramp 17->11us) + global atomic
// TICKET for tiles 512..767 (disjoint outputs -> order-independent, G16-safe).
__global__ __launch_bounds__(512, 4) void g2_kernel(const unsigned char* __restrict__ base_ready,
                                                    const float* __restrict__ Wo,    // [256][98304] layer slice
                                                    const float* __restrict__ biasL, // [32*3072]
                                                    const float* __restrict__ boL,   // [98304]
                                                    const float* __restrict__ rx,    // [256*3072]
                                                    float* __restrict__ partial,
                                                    int* __restrict__ tk) {
    __shared__ __align__(16) unsigned char ldsA[2][20480];  // [m][32k bf16 + pad]
    __shared__ __align__(16) unsigned char ldsW[2][10240];  // [n][32k bf16 + pad]
    __shared__ int s_next;

    int t = threadIdx.x;
    int lane = t & 63, wv = t >> 6;
    int wm = wv >> 1, wn = wv & 1;
    int lrow = lane & 15, lk = lane >> 4;
    int nW = t & 127, kq = t >> 7;   // W staging role: kq in 0..3

#define DMA_A(S, BUF) {                                                                  \
    const unsigned char* gA = base_ready + (S) * 20480;                                  \
    __builtin_amdgcn_global_load_lds(                                                    \
        (const __attribute__((address_space(1))) unsigned int*)(gA + t * 16),            \
        (__attribute__((address_space(3))) unsigned int*)(&ldsA[BUF][0] + wv * 1024),    \
        16, 0, 0);                                                                       \
    __builtin_amdgcn_global_load_lds(                                                    \
        (const __attribute__((address_space(1))) unsigned int*)(gA + 8192 + t * 16),     \
        (__attribute__((address_space(3))) unsigned int*)(&ldsA[BUF][0] + 8192 + wv * 1024), \
        16, 0, 0);                                                                       \
    if (wv < 4)                                                                          \
        __builtin_amdgcn_global_load_lds(                                                \
            (const __attribute__((address_space(1))) unsigned int*)(gA + 16384 + t * 16),\
            (__attribute__((address_space(3))) unsigned int*)(&ldsA[BUF][0] + 16384 + wv * 1024), \
            16, 0, 0); }

#define LOADW_(S, WF) {                                                                  \
    const float* gp0 = Wo + (size_t)((S) * 32 + kq * 4) * OD_ + ncol0 + nW;              \
    WF[0] = gp0[0]; WF[1] = gp0[OD_]; WF[2] = gp0[2 * OD_]; WF[3] = gp0[3 * OD_];        \
    const float* gp1 = gp0 + (size_t)16 * OD_;                                           \
    WF[4] = gp1[0]; WF[5] = gp1[OD_]; WF[6] = gp1[2 * OD_]; WF[7] = gp1[3 * OD_]; }

#define WRITEW_(BUF, WF) {                                                               \
    uint2 pk0, pk1;                                                                      \
    pk0.x = (unsigned)f2bf(WF[0]) | ((unsigned)f2bf(WF[1]) << 16);                       \
    pk0.y = (unsigned)f2bf(WF[2]) | ((unsigned)f2bf(WF[3]) << 16);                       \
    *(uint2*)(ldsW[BUF] + nW * 80 + kq * 8) = pk0;                                       \
    pk1.x = (unsigned)f2bf(WF[4]) | ((unsigned)f2bf(WF[5]) << 16);                       \
    pk1.y = (unsigned)f2bf(WF[6]) | ((unsigned)f2bf(WF[7]) << 16);                       \
    *(uint2*)(ldsW[BUF] + nW * 80 + 32 + kq * 8) = pk1; }

    int tile = blockIdx.x;
    while (tile < 768) {
        int ncol0 = tile * 128;
        int o = tile / 24;
        int dbase = (tile % 24) * 128;

        f32x4 acc[4][4];
#pragma unroll
        for (int mi = 0; mi < 4; ++mi)
#pragma unroll
            for (int ni = 0; ni < 4; ++ni) acc[mi][ni] = 0.f;

        float wfX[8], wfY[8];

        DMA_A(0, 0);
        LOADW_(0, wfX);
        LOADW_(1, wfY);
        WRITEW_(0, wfX);
        asm volatile("s_waitcnt lgkmcnt(0)" ::: "memory");
        __builtin_amdgcn_s_barrier();

#pragma unroll 2
        for (int s = 0; s < 8; ++s) {
            int pb = s & 1;
            if (s < 7) DMA_A(s + 1, pb ^ 1);
            if (s < 6) {
                if ((s & 1) == 0) { LOADW_(s + 2, wfX); }
                else              { LOADW_(s + 2, wfY); }
            }
            short8 bfr[4];
#pragma unroll
            for (int ni = 0; ni < 4; ++ni) {
                int nn = wn * 64 + ni * 16 + lrow;
                bfr[ni] = *(const short8*)(ldsW[pb] + nn * 80 + lk * 16);
            }
#pragma unroll
            for (int mi = 0; mi < 4; ++mi) {
                int row = wm * 64 + mi * 16 + lrow;
                short8 af = *(const short8*)(ldsA[pb] + row * 80 + lk * 16);
#pragma unroll
                for (int ni = 0; ni < 4; ++ni)
                    acc[mi][ni] = __builtin_amdgcn_mfma_f32_16x16x32_bf16(af, bfr[ni], acc[mi][ni], 0, 0, 0);
            }
            if (s < 7) {
                if ((s & 1) == 0) { WRITEW_(pb ^ 1, wfY); }
                else              { WRITEW_(pb ^ 1, wfX); }
                if (s < 6) asm volatile("s_waitcnt vmcnt(8) lgkmcnt(0)" ::: "memory");  // drain A(s+1); keep W(s+2)
                else       asm volatile("s_waitcnt vmcnt(0) lgkmcnt(0)" ::: "memory");  // last: drain A(7)
                __builtin_amdgcn_s_barrier();
            }
        }

        // epilogue: loss partials
        float q[4];
#pragma unroll
        for (int ni = 0; ni < 4; ++ni) {
            int dcol = dbase + wn * 64 + ni * 16 + lrow;
            q[ni] = biasL[o * D_ + dcol] + boL[o * D_ + dcol];
        }
        float ssum[4][4];
#pragma unroll
        for (int mi = 0; mi < 4; ++mi)
#pragma unroll
            for (int r = 0; r < 4; ++r) ssum[mi][r] = 0.f;
#pragma unroll
        for (int mi = 0; mi < 4; ++mi) {
#pragma unroll
            for (int ni = 0; ni < 4; ++ni) {
                int dcol = dbase + wn * 64 + ni * 16 + lrow;
#pragma unroll
                for (int r = 0; r < 4; ++r) {
                    int rowm = wm * 64 + mi * 16 + lk * 4 + r;
                    float tv = acc[mi][ni][r] + rx[rowm * D_ + dcol] + q[ni];
                    ssum[mi][r] += tv * tv;
                }
            }
        }
#pragma unroll
        for (int mi = 0; mi < 4; ++mi)
#pragma unroll
            for (int r = 0; r < 4; ++r) {
                float v = ssum[mi][r];
                v += __shfl_xor(v, 1);
                v += __shfl_xor(v, 2);
                v += __shfl_xor(v, 4);
                v += __shfl_xor(v, 8);
                if (lrow == 0) {
                    int rowm = wm * 64 + mi * 16 + lk * 4 + r;
                    partial[(rowm * OPT_ + o) * 48 + (tile % 24) * 2 + wn] = v;
                }
            }

        // next tile via ticket (syncthreads also fences LDS reuse)
        __syncthreads();
        if (t == 0) s_next = atomicAdd(tk, 1);
        __syncthreads();
        tile = s_next;
    }
#undef DMA_A
#undef LOADW_
#undef WRITEW_
}

// ---------------------------------------------------------------------------
// C: per-b argmin over 32 options (tie-break lowest index = jnp.argmin).
// 64 blocks x 4 b each (ramp ~1.4us).
__global__ __launch_bounds__(256) void c_kernel(const float* __restrict__ partial,
                                                int* __restrict__ idxbuf,
                                                float* __restrict__ enc, int layer) {
    __shared__ float ls[32];
    int t = threadIdx.x;
    int oo = t >> 3, j8 = t & 7;
    for (int bb2 = 0; bb2 < 4; ++bb2) {
        int b = blockIdx.x * 4 + bb2;
        const float* pp = partial + (b * OPT_ + oo) * 48;
        float v = 0.f;
#pragma unroll
        for (int j = 0; j < 6; ++j) v += pp[j8 + 8 * j];
        v += __shfl_xor(v, 1);
        v += __shfl_xor(v, 2);
        v += __shfl_xor(v, 4);
        if (j8 == 0) ls[oo] = v;
        __syncthreads();
        if (t < 32) {
            float mv = ls[t];
            int mi = t;
#pragma unroll
            for (int m = 16; m >= 1; m >>= 1) {
                float ov = __shfl_xor(mv, m);
                int oi = __shfl_xor(mi, m);
                if (ov < mv || (ov == mv && oi < mi)) { mv = ov; mi = oi; }
            }
            if (t == 0) {
                idxbuf[b] = mi;
                enc[b * NL_ + layer] = (float)mi;
            }
        }
        __syncthreads();
    }
}

// ---------------------------------------------------------------------------
// D: recompute selected option. Bucketing FUSED via deterministic rank-scan
// (no atomics, identical partition in every block). grid (32 x 12) = 384
// blocks, each handles work items j = bx, bx+32, ... (compact, no empties).
__global__ __launch_bounds__(256) void d_kernel(const int* __restrict__ idxbuf,
                                                const float* __restrict__ basef,
                                                const float* __restrict__ Wo,
                                                const float* __restrict__ boL,
                                                const float* __restrict__ biasL,
                                                const float* __restrict__ x,
                                                float* __restrict__ cur,
                                                float* __restrict__ rx) {
    __shared__ int sidx[256];
    __shared__ int scnt[32];
    __shared__ int snch[32];
    __shared__ int chunk_b[8];
    __shared__ float basL[8][256];
    int t = threadIdx.x;
    int dt = blockIdx.y;

    sidx[t] = idxbuf[t];
    __syncthreads();
    if (t < 32) {
        int c = 0;
        for (int b = 0; b < 256; ++b) c += (sidx[b] == t);
        scnt[t] = c;
        snch[t] = (c + 7) >> 3;
    }
    __syncthreads();
    int myo = sidx[t];
    int myrank = 0;
    for (int b = 0; b < t; ++b) myrank += (sidx[b] == myo);

    for (int j = blockIdx.x; ; j += 32) {
        int o = -1, ch = 0, pre = 0;
        for (int oo = 0; oo < 32; ++oo) {
            int n = snch[oo];
            if (j < pre + n) { o = oo; ch = j - pre; break; }
            pre += n;
        }
        if (o < 0) break;
        int cnt = scnt[o];
        int c0 = ch * 8;
        int rem = cnt - c0;
        if (rem > 8) rem = 8;

        __syncthreads();
        if (myo == o && myrank >= c0 && myrank < c0 + 8) chunk_b[myrank - c0] = t;
        __syncthreads();

        int bidx[8];
#pragma unroll
        for (int g = 0; g < 8; ++g) bidx[g] = chunk_b[(g < rem) ? g : (rem - 1)];
#pragma unroll
        for (int g = 0; g < 8; ++g) basL[g][t] = basef[bidx[g] * H_ + t];
        __syncthreads();

        int d = dt * 256 + t;
        const float* wp = Wo + (size_t)o * D_ + d;
        size_t nn = (size_t)o * D_ + d;
        float bov = boL[nn];
        float biv = biasL[nn];

        float acc[8] = {0.f, 0.f, 0.f, 0.f, 0.f, 0.f, 0.f, 0.f};
        for (int k0 = 0; k0 < 256; k0 += 8) {
            float w[8];
#pragma unroll
            for (int u = 0; u < 8; ++u) w[u] = wp[(size_t)(k0 + u) * OD_];
#pragma unroll
            for (int h = 0; h < 2; ++h) {
                int kb = k0 + h * 4;
                f32x4 bv[8];
#pragma unroll
                for (int g = 0; g < 8; ++g) bv[g] = *(const f32x4*)&basL[g][kb];
#pragma unroll
                for (int u = 0; u < 4; ++u) {
                    float wu = w[h * 4 + u];
#pragma unroll
                    for (int g = 0; g < 8; ++g) acc[g] += bv[g][u] * wu;   // k ascending
                }
            }
        }
#pragma unroll
        for (int g = 0; g < 8; ++g) {
            if (g < rem) {
                int b = bidx[g];
                float outv = cur[b * D_ + d] + acc[g] + bov + biv;
                cur[b * D_ + d] = outv;
                rx[b * D_ + d] = outv - x[b * D_ + d];
            }
        }
    }
}

// ---------------------------------------------------------------------------
extern "C" void kernel_launch(void* const* d_in, const int* in_sizes, int n_in,
                              void* d_out, int out_size, void* d_ws, size_t ws_size,
                              hipStream_t stream) {
    const float* x    = (const float*)d_in[0];  // [256][3072]
    const float* Wb   = (const float*)d_in[1];  // [3072][256]
    const float* bb   = (const float*)d_in[2];  // [256]
    const float* Wo   = (const float*)d_in[3];  // [4][256][98304]
    const float* bo   = (const float*)d_in[4];  // [4][98304]
    const float* bias = (const float*)d_in[5];  // [4][32][3072]

    float* out = (float*)d_out;
    float* enc = out;            // [256][4] (indices as float)
    float* cur = out + 1024;     // [256][3072] reconstruction

    float* ws = (float*)d_ws;
    float* zpart   = ws;                          // 8*256*256 = 524288
    float* partial = ws + 524288;                 // 256*32*48 = 393216
    float* rx      = ws + 917504;                 // 256*3072  = 786432
    float* basef   = ws + 1703936;                // 256*256   = 65536
    unsigned char* base_ready = (unsigned char*)(ws + 1769472);  // 163840 B
    int* idxbuf    = (int*)(ws + 1810432);        // 256 ints
    int* g2tk      = (int*)(ws + 1810688);        // 4 ints

    init_kernel<<<256, 256, 0, stream>>>(x, cur, rx, zpart, g2tk);

    for (int i = 0; i < NL_; ++i) {
        const float* WoL   = Wo + (size_t)i * H_ * OD_;
        const float* boLp  = bo + (size_t)i * OD_;
        const float* biasL = bias + (size_t)i * OD_;
        if (i > 0) gemm1_kernel<<<256, 256, 0, stream>>>(cur, Wb, zpart);
        e_kernel<<<64, 256, 0, stream>>>(zpart, bb, base_ready, basef);
        g2_kernel<<<512, 512, 0, stream>>>(base_ready, WoL, biasL, boLp, rx, partial, g2tk + i);
        c_kernel<<<64, 256, 0, stream>>>(partial, idxbuf, enc, i);
        d_kernel<<<dim3(32, 12), 256, 0, stream>>>(idxbuf, basef, WoL, boLp, biasL, x, cur, rx);
    }
}

// Round 11
// 452.377 us; speedup vs baseline: 3.6456x; 1.1062x over previous
//
#include <hip/hip_runtime.h>
#include <hip/hip_bf16.h>

// Sizes
#define B_ 256
#define D_ 3072
#define H_ 256
#define OPT_ 32
#define OD_ 98304       // OPT_*D_
#define NL_ 4

typedef __attribute__((ext_vector_type(8))) short short8;
typedef __attribute__((ext_vector_type(4))) float f32x4;

__device__ __forceinline__ unsigned short f2bf(float f) {
    unsigned int u = __float_as_uint(f);
    unsigned int r = (u + 0x7FFFu + ((u >> 16) & 1u)) >> 16;
    return (unsigned short)r;
}

// ---------------------------------------------------------------------------
// init: cur = 0, rx = -x, zpart = 0.  (R7 verbatim)
__global__ __launch_bounds__(256) void init_kernel(const float* __restrict__ x,
                                                   float* __restrict__ cur,
                                                   float* __restrict__ rx,
                                                   float* __restrict__ zpart) {
    int gid0 = blockIdx.x * 256 + threadIdx.x;   // 131072 threads
    for (int g = gid0; g < B_ * D_; g += 131072) {
        cur[g] = 0.f;
        rx[g] = -x[g];
    }
    for (int g = gid0; g < 16 * B_ * H_; g += 131072) zpart[g] = 0.f;
}

// ---------------------------------------------------------------------------
// gemm1 (R7 verbatim): zpart[ks][b][h], 512 blocks (16 kslices x 32 bgroups)
__global__ __launch_bounds__(256) void gemm1_kernel(const float* __restrict__ cur,
                                                    const float* __restrict__ Wb,
                                                    float* __restrict__ zpart) {
    int t = threadIdx.x;
    int ks = blockIdx.x >> 5;     // 0..15
    int bg = blockIdx.x & 31;     // 0..31
    const float* wp = Wb + (size_t)ks * 192 * H_ + t;
    const float* cp = cur + (size_t)(bg * 8) * D_ + ks * 192;
    float acc[8] = {0.f, 0.f, 0.f, 0.f, 0.f, 0.f, 0.f, 0.f};
#pragma unroll 4
    for (int dd = 0; dd < 192; ++dd) {
        float w = wp[(size_t)dd * H_];
#pragma unroll
        for (int g = 0; g < 8; ++g) acc[g] += cp[(size_t)g * D_ + dd] * w;
    }
#pragma unroll
    for (int g = 0; g < 8; ++g)
        zpart[ks * (B_ * H_) + (bg * 8 + g) * H_ + t] = acc[g];
}

// ---------------------------------------------------------------------------
// E (R7 verbatim): base = relu(sum_ks zpart + bb) -> bf16 image + f32 basef.
__global__ __launch_bounds__(256) void e_kernel(const float* __restrict__ zpart,
                                                const float* __restrict__ bb,
                                                unsigned char* __restrict__ base_ready,
                                                float* __restrict__ basef) {
    int m = blockIdx.x, k = threadIdx.x;
    float z = bb[k];
#pragma unroll
    for (int ks = 0; ks < 16; ++ks) z += zpart[ks * (B_ * H_) + m * H_ + k];
    z = z > 0.f ? z : 0.f;
    *(unsigned short*)(base_ready + (k >> 5) * 20480 + m * 80 + (k & 31) * 2) = f2bf(z);
    basef[m * H_ + k] = z;
}

// ---------------------------------------------------------------------------
// G2 v11: 1024 threads (16 waves, 4m x 4n, per-wave 64x32 -> acc 32 VGPR),
// BK=64 (4 barriers/tile, W as two 32k sub-images in the proven 80B rows),
// A-fragments per-wave from L2-hot base_ready directly into registers (same
// byte addresses as old DMA+LDS-read composite; no A-DMA -> barriers are
// lgkmcnt(0)-only, W loads free-fly). W 2-deep X/Y: 64KB in flight >> 22KB
// latency-BW product. Grid 768 = exactly 3 tiles/CU, no partial tail.
// K-chunk accumulation order identical to R7 (8 x 32k ascending).
__global__ __launch_bounds__(1024, 4) void g2_kernel(const unsigned char* __restrict__ base_ready,
                                                     const float* __restrict__ Wo,    // [256][98304] layer slice
                                                     const float* __restrict__ biasL, // [32*3072]
                                                     const float* __restrict__ boL,   // [98304]
                                                     const float* __restrict__ rx,    // [256*3072]
                                                     float* __restrict__ partial) {
    __shared__ __align__(16) unsigned char ldsW[2][2][10240];  // [buf][ks][128n x 80B]

    int t = threadIdx.x;
    int lane = t & 63, wv = t >> 6;       // wv 0..15
    int tile = blockIdx.x;
    int ncol0 = tile * 128;
    int o = tile / 24;                    // 24 tiles per option
    int dbase = (tile % 24) * 128;

    int wm = wv >> 2, wn = wv & 3;        // 4 m-waves x 4 n-waves
    int lrow = lane & 15, lk = lane >> 4;
    int nW = t & 127, kq = t >> 7;        // W staging: kq 0..7 (8 k's each)

    f32x4 acc[4][2];
#pragma unroll
    for (int mi = 0; mi < 4; ++mi)
#pragma unroll
        for (int ni = 0; ni < 2; ++ni) acc[mi][ni] = 0.f;

    float wfX[8], wfY[8];
    short8 afX[4], afY[4];

#define LOADW_(S, WF) {                                                                  \
    const float* gp = Wo + (size_t)((S) * 64 + kq * 8) * OD_ + ncol0 + nW;               \
    WF[0] = gp[0];            WF[1] = gp[OD_];                                           \
    WF[2] = gp[2 * (size_t)OD_]; WF[3] = gp[3 * (size_t)OD_];                            \
    WF[4] = gp[4 * (size_t)OD_]; WF[5] = gp[5 * (size_t)OD_];                            \
    WF[6] = gp[6 * (size_t)OD_]; WF[7] = gp[7 * (size_t)OD_]; }

#define WRITEW_(BUF, WF) {                                                               \
    uint4 pk;                                                                            \
    pk.x = (unsigned)f2bf(WF[0]) | ((unsigned)f2bf(WF[1]) << 16);                        \
    pk.y = (unsigned)f2bf(WF[2]) | ((unsigned)f2bf(WF[3]) << 16);                        \
    pk.z = (unsigned)f2bf(WF[4]) | ((unsigned)f2bf(WF[5]) << 16);                        \
    pk.w = (unsigned)f2bf(WF[6]) | ((unsigned)f2bf(WF[7]) << 16);                        \
    *(uint4*)(&ldsW[BUF][kq >> 2][0] + nW * 80 + (kq & 3) * 16) = pk; }

#define AF_(G, AF) {                                                                     \
    const unsigned char* gA = base_ready + (G) * 20480;                                  \
    AF[0] = *(const short8*)(gA + (wm * 64 +  0 + lrow) * 80 + lk * 16);                 \
    AF[1] = *(const short8*)(gA + (wm * 64 + 16 + lrow) * 80 + lk * 16);                 \
    AF[2] = *(const short8*)(gA + (wm * 64 + 32 + lrow) * 80 + lk * 16);                 \
    AF[3] = *(const short8*)(gA + (wm * 64 + 48 + lrow) * 80 + lk * 16); }

    // prologue: W(0)->X, W(1)->Y in flight; A group 0 in flight; write W(0)
    LOADW_(0, wfX);
    LOADW_(1, wfY);
    AF_(0, afX);
    WRITEW_(0, wfX);
    asm volatile("s_waitcnt lgkmcnt(0)" ::: "memory");
    __builtin_amdgcn_s_barrier();

#pragma unroll 2
    for (int s = 0; s < 4; ++s) {
        int cur = s & 1;
        AF_(2 * s + 1, afY);                       // prefetch A group ks=1
        if (s < 2) {
            if ((s & 1) == 0) { LOADW_(s + 2, wfX); }
            else              { LOADW_(s + 2, wfY); }
        }
        // group ks=0 (A in afX)
        short8 bfr0[2];
#pragma unroll
        for (int ni = 0; ni < 2; ++ni)
            bfr0[ni] = *(const short8*)(&ldsW[cur][0][0] + (wn * 32 + ni * 16 + lrow) * 80 + lk * 16);
#pragma unroll
        for (int mi = 0; mi < 4; ++mi)
#pragma unroll
            for (int ni = 0; ni < 2; ++ni)
                acc[mi][ni] = __builtin_amdgcn_mfma_f32_16x16x32_bf16(afX[mi], bfr0[ni], acc[mi][ni], 0, 0, 0);
        if (s < 3) AF_(2 * s + 2, afX);            // prefetch next step's ks=0
        // group ks=1 (A in afY)
        short8 bfr1[2];
#pragma unroll
        for (int ni = 0; ni < 2; ++ni)
            bfr1[ni] = *(const short8*)(&ldsW[cur][1][0] + (wn * 32 + ni * 16 + lrow) * 80 + lk * 16);
#pragma unroll
        for (int mi = 0; mi < 4; ++mi)
#pragma unroll
            for (int ni = 0; ni < 2; ++ni)
                acc[mi][ni] = __builtin_amdgcn_mfma_f32_16x16x32_bf16(afY[mi], bfr1[ni], acc[mi][ni], 0, 0, 0);
        if (s < 3) {
            if ((s & 1) == 0) { WRITEW_(cur ^ 1, wfY); }
            else              { WRITEW_(cur ^ 1, wfX); }
            asm volatile("s_waitcnt lgkmcnt(0)" ::: "memory");
            __builtin_amdgcn_s_barrier();
        }
    }

#undef LOADW_
#undef WRITEW_
#undef AF_

    // epilogue: loss partials (96 per (b,o): 24 tiles x 4 wn)
    float q[2];
#pragma unroll
    for (int ni = 0; ni < 2; ++ni) {
        int dcol = dbase + wn * 32 + ni * 16 + lrow;
        q[ni] = biasL[o * D_ + dcol] + boL[o * D_ + dcol];
    }
    float ssum[4][4];
#pragma unroll
    for (int mi = 0; mi < 4; ++mi)
#pragma unroll
        for (int r = 0; r < 4; ++r) ssum[mi][r] = 0.f;
#pragma unroll
    for (int mi = 0; mi < 4; ++mi) {
#pragma unroll
        for (int ni = 0; ni < 2; ++ni) {
            int dcol = dbase + wn * 32 + ni * 16 + lrow;
#pragma unroll
            for (int r = 0; r < 4; ++r) {
                int rowm = wm * 64 + mi * 16 + lk * 4 + r;
                float tv = acc[mi][ni][r] + rx[rowm * D_ + dcol] + q[ni];
                ssum[mi][r] += tv * tv;
            }
        }
    }
#pragma unroll
    for (int mi = 0; mi < 4; ++mi)
#pragma unroll
        for (int r = 0; r < 4; ++r) {
            float v = ssum[mi][r];
            v += __shfl_xor(v, 1);
            v += __shfl_xor(v, 2);
            v += __shfl_xor(v, 4);
            v += __shfl_xor(v, 8);
            if (lrow == 0) {
                int rowm = wm * 64 + mi * 16 + lk * 4 + r;
                partial[(rowm * OPT_ + o) * 96 + (tile % 24) * 4 + wn] = v;
            }
        }
}

// ---------------------------------------------------------------------------
// C: per-b argmin over 32 options, 96 partials each (tie-break lowest index).
__global__ __launch_bounds__(256) void c_kernel(const float* __restrict__ partial,
                                                int* __restrict__ idxbuf,
                                                float* __restrict__ enc, int layer) {
    __shared__ float ls[32];
    int b = blockIdx.x, t = threadIdx.x;
    int oo = t >> 3, j8 = t & 7;
    const float* pp = partial + (b * OPT_ + oo) * 96;
    float v = 0.f;
#pragma unroll
    for (int j = 0; j < 12; ++j) v += pp[j8 + 8 * j];
    v += __shfl_xor(v, 1);
    v += __shfl_xor(v, 2);
    v += __shfl_xor(v, 4);
    if (j8 == 0) ls[oo] = v;
    __syncthreads();
    if (t < 32) {
        float mv = ls[t];
        int mi = t;
#pragma unroll
        for (int m = 16; m >= 1; m >>= 1) {
            float ov = __shfl_xor(mv, m);
            int oi = __shfl_xor(mi, m);
            if (ov < mv || (ov == mv && oi < mi)) { mv = ov; mi = oi; }
        }
        if (t == 0) {
            idxbuf[b] = mi;
            enc[b * NL_ + layer] = (float)mi;
        }
    }
}

// ---------------------------------------------------------------------------
// D (R7 verbatim): bucketed recompute, rank-scan fused, grid (32 x 12).
__global__ __launch_bounds__(256) void d_kernel(const int* __restrict__ idxbuf,
                                                const float* __restrict__ basef,
                                                const float* __restrict__ Wo,
                                                const float* __restrict__ boL,
                                                const float* __restrict__ biasL,
                                                const float* __restrict__ x,
                                                float* __restrict__ cur,
                                                float* __restrict__ rx) {
    __shared__ int sidx[256];
    __shared__ int scnt[32];
    __shared__ int snch[32];
    __shared__ int chunk_b[8];
    __shared__ float basL[8][256];
    int t = threadIdx.x;
    int dt = blockIdx.y;

    sidx[t] = idxbuf[t];
    __syncthreads();
    if (t < 32) {
        int c = 0;
        for (int b = 0; b < 256; ++b) c += (sidx[b] == t);
        scnt[t] = c;
        snch[t] = (c + 7) >> 3;
    }
    __syncthreads();
    int myo = sidx[t];
    int myrank = 0;
    for (int b = 0; b < t; ++b) myrank += (sidx[b] == myo);

    for (int j = blockIdx.x; ; j += 32) {
        int o = -1, ch = 0, pre = 0;
        for (int oo = 0; oo < 32; ++oo) {
            int n = snch[oo];
            if (j < pre + n) { o = oo; ch = j - pre; break; }
            pre += n;
        }
        if (o < 0) break;
        int cnt = scnt[o];
        int c0 = ch * 8;
        int rem = cnt - c0;
        if (rem > 8) rem = 8;

        __syncthreads();
        if (myo == o && myrank >= c0 && myrank < c0 + 8) chunk_b[myrank - c0] = t;
        __syncthreads();

        int bidx[8];
#pragma unroll
        for (int g = 0; g < 8; ++g) bidx[g] = chunk_b[(g < rem) ? g : (rem - 1)];
#pragma unroll
        for (int g = 0; g < 8; ++g) basL[g][t] = basef[bidx[g] * H_ + t];
        __syncthreads();

        int d = dt * 256 + t;
        const float* wp = Wo + (size_t)o * D_ + d;
        size_t nn = (size_t)o * D_ + d;
        float bov = boL[nn];
        float biv = biasL[nn];

        float acc[8] = {0.f, 0.f, 0.f, 0.f, 0.f, 0.f, 0.f, 0.f};
        for (int k0 = 0; k0 < 256; k0 += 8) {
            float w[8];
#pragma unroll
            for (int u = 0; u < 8; ++u) w[u] = wp[(size_t)(k0 + u) * OD_];
#pragma unroll
            for (int h = 0; h < 2; ++h) {
                int kb = k0 + h * 4;
                f32x4 bv[8];
#pragma unroll
                for (int g = 0; g < 8; ++g) bv[g] = *(const f32x4*)&basL[g][kb];
#pragma unroll
                for (int u = 0; u < 4; ++u) {
                    float wu = w[h * 4 + u];
#pragma unroll
                    for (int g = 0; g < 8; ++g) acc[g] += bv[g][u] * wu;   // k ascending
                }
            }
        }
#pragma unroll
        for (int g = 0; g < 8; ++g) {
            if (g < rem) {
                int b = bidx[g];
                float outv = cur[b * D_ + d] + acc[g] + bov + biv;
                cur[b * D_ + d] = outv;
                rx[b * D_ + d] = outv - x[b * D_ + d];
            }
        }
    }
}

// ---------------------------------------------------------------------------
extern "C" void kernel_launch(void* const* d_in, const int* in_sizes, int n_in,
                              void* d_out, int out_size, void* d_ws, size_t ws_size,
                              hipStream_t stream) {
    const float* x    = (const float*)d_in[0];  // [256][3072]
    const float* Wb   = (const float*)d_in[1];  // [3072][256]
    const float* bb   = (const float*)d_in[2];  // [256]
    const float* Wo   = (const float*)d_in[3];  // [4][256][98304]
    const float* bo   = (const float*)d_in[4];  // [4][98304]
    const float* bias = (const float*)d_in[5];  // [4][32][3072]

    float* out = (float*)d_out;
    float* enc = out;            // [256][4] (indices as float)
    float* cur = out + 1024;     // [256][3072] reconstruction

    float* ws = (float*)d_ws;
    float* zpart   = ws;                          // 16*256*256 = 1048576
    float* partial = ws + 1048576;                // 256*32*96  = 786432
    float* rx      = ws + 1835008;                // 256*3072   = 786432
    float* basef   = ws + 2621440;                // 256*256    = 65536
    unsigned char* base_ready = (unsigned char*)(ws + 2686976);  // 163840 B
    int* idxbuf    = (int*)(ws + 2727936);        // 256 ints

    init_kernel<<<512, 256, 0, stream>>>(x, cur, rx, zpart);

    for (int i = 0; i < NL_; ++i) {
        const float* WoL   = Wo + (size_t)i * H_ * OD_;
        const float* boLp  = bo + (size_t)i * OD_;
        const float* biasL = bias + (size_t)i * OD_;
        if (i > 0) gemm1_kernel<<<512, 256, 0, stream>>>(cur, Wb, zpart);
        e_kernel<<<256, 256, 0, stream>>>(zpart, bb, base_ready, basef);
        g2_kernel<<<768, 1024, 0, stream>>>(base_ready, WoL, biasL, boLp, rx, partial);
        c_kernel<<<256, 256, 0, stream>>>(partial, idxbuf, enc, i);
        d_kernel<<<dim3(32, 12), 256, 0, stream>>>(idxbuf, basef, WoL, boLp, biasL, x, cur, rx);
    }
}

// Round 12
// 390.261 us; speedup vs baseline: 4.2259x; 1.1592x over previous
//
#include <hip/hip_runtime.h>
#include <hip/hip_bf16.h>

// Sizes
#define B_ 256
#define D_ 3072
#define H_ 256
#define OPT_ 32
#define OD_ 98304       // OPT_*D_
#define NL_ 4

typedef __attribute__((ext_vector_type(8))) short short8;
typedef __attribute__((ext_vector_type(4))) float f32x4;

__device__ __forceinline__ unsigned short f2bf(float f) {
    unsigned int u = __float_as_uint(f);
    unsigned int r = (u + 0x7FFFu + ((u >> 16) & 1u)) >> 16;
    return (unsigned short)r;
}

// ---------------------------------------------------------------------------
// E: base = relu(z + bb) -> bf16 image + f32 basef.
// Layer 0: z = bb (cur==0, so base = relu(bb) -- init kernel eliminated).
// Layers 1-3: z = bb + sum_{dt=0..11} zpart2[dt][m][k] (written by fused d).
__global__ __launch_bounds__(256) void e_kernel(const float* __restrict__ zpart2,
                                                const float* __restrict__ bb,
                                                unsigned char* __restrict__ base_ready,
                                                float* __restrict__ basef,
                                                int first) {
    int m = blockIdx.x, k = threadIdx.x;
    float z = bb[k];
    if (!first) {
#pragma unroll
        for (int dt = 0; dt < 12; ++dt) z += zpart2[dt * (B_ * H_) + m * H_ + k];
    }
    z = z > 0.f ? z : 0.f;
    *(unsigned short*)(base_ready + (k >> 5) * 20480 + m * 80 + (k & 31) * 2) = f2bf(z);
    basef[m * H_ + k] = z;
}

// ---------------------------------------------------------------------------
// G2 (R7 schedule verbatim): fused GEMM (256x98304, K=256, bf16 MFMA) +
// squared-loss partials. rp/rsign: layer 0 reads x with rsign=-1 (exact -x,
// replaces the init-written rx); layers 1-3 read rx with rsign=+1 (exact).
__global__ __launch_bounds__(512, 4) void g2_kernel(const unsigned char* __restrict__ base_ready,
                                                    const float* __restrict__ Wo,    // [256][98304] layer slice
                                                    const float* __restrict__ biasL, // [32*3072]
                                                    const float* __restrict__ boL,   // [98304]
                                                    const float* __restrict__ rp,    // rx or x
                                                    float rsign,
                                                    float* __restrict__ partial) {
    __shared__ __align__(16) unsigned char ldsA[2][20480];  // [m][32k bf16 + pad]
    __shared__ __align__(16) unsigned char ldsW[2][10240];  // [n][32k bf16 + pad]

    int t = threadIdx.x;
    int lane = t & 63, wv = t >> 6;
    int bx = blockIdx.x;
    int ncol0 = bx * 128;
    int o = bx / 24;                 // 24 blocks per option
    int dbase = (bx % 24) * 128;

    int wm = wv >> 1, wn = wv & 1;
    int lrow = lane & 15, lk = lane >> 4;
    int nW = t & 127, kq = t >> 7;   // W staging role: kq in 0..3

    f32x4 acc[4][4];
#pragma unroll
    for (int mi = 0; mi < 4; ++mi)
#pragma unroll
        for (int ni = 0; ni < 4; ++ni) acc[mi][ni] = 0.f;

    float wfX[8], wfY[8];

#define DMA_A(S, BUF) {                                                                  \
    const unsigned char* gA = base_ready + (S) * 20480;                                  \
    __builtin_amdgcn_global_load_lds(                                                    \
        (const __attribute__((address_space(1))) unsigned int*)(gA + t * 16),            \
        (__attribute__((address_space(3))) unsigned int*)(&ldsA[BUF][0] + wv * 1024),    \
        16, 0, 0);                                                                       \
    __builtin_amdgcn_global_load_lds(                                                    \
        (const __attribute__((address_space(1))) unsigned int*)(gA + 8192 + t * 16),     \
        (__attribute__((address_space(3))) unsigned int*)(&ldsA[BUF][0] + 8192 + wv * 1024), \
        16, 0, 0);                                                                       \
    if (wv < 4)                                                                          \
        __builtin_amdgcn_global_load_lds(                                                \
            (const __attribute__((address_space(1))) unsigned int*)(gA + 16384 + t * 16),\
            (__attribute__((address_space(3))) unsigned int*)(&ldsA[BUF][0] + 16384 + wv * 1024), \
            16, 0, 0); }

#define LOADW_(S, WF) {                                                                  \
    const float* gp0 = Wo + (size_t)((S) * 32 + kq * 4) * OD_ + ncol0 + nW;              \
    WF[0] = gp0[0]; WF[1] = gp0[OD_]; WF[2] = gp0[2 * OD_]; WF[3] = gp0[3 * OD_];        \
    const float* gp1 = gp0 + (size_t)16 * OD_;                                           \
    WF[4] = gp1[0]; WF[5] = gp1[OD_]; WF[6] = gp1[2 * OD_]; WF[7] = gp1[3 * OD_]; }

#define WRITEW_(BUF, WF) {                                                               \
    uint2 pk0, pk1;                                                                      \
    pk0.x = (unsigned)f2bf(WF[0]) | ((unsigned)f2bf(WF[1]) << 16);                       \
    pk0.y = (unsigned)f2bf(WF[2]) | ((unsigned)f2bf(WF[3]) << 16);                       \
    *(uint2*)(ldsW[BUF] + nW * 80 + kq * 8) = pk0;                                       \
    pk1.x = (unsigned)f2bf(WF[4]) | ((unsigned)f2bf(WF[5]) << 16);                       \
    pk1.y = (unsigned)f2bf(WF[6]) | ((unsigned)f2bf(WF[7]) << 16);                       \
    *(uint2*)(ldsW[BUF] + nW * 80 + 32 + kq * 8) = pk1; }

    DMA_A(0, 0);
    LOADW_(0, wfX);
    LOADW_(1, wfY);
    WRITEW_(0, wfX);
    asm volatile("s_waitcnt lgkmcnt(0)" ::: "memory");
    __builtin_amdgcn_s_barrier();

#pragma unroll 2
    for (int s = 0; s < 8; ++s) {
        int cur = s & 1;
        if (s < 7) DMA_A(s + 1, cur ^ 1);
        if (s < 6) {
            if ((s & 1) == 0) { LOADW_(s + 2, wfX); }
            else              { LOADW_(s + 2, wfY); }
        }
        short8 bfr[4];
#pragma unroll
        for (int ni = 0; ni < 4; ++ni) {
            int nn = wn * 64 + ni * 16 + lrow;
            bfr[ni] = *(const short8*)(ldsW[cur] + nn * 80 + lk * 16);
        }
#pragma unroll
        for (int mi = 0; mi < 4; ++mi) {
            int row = wm * 64 + mi * 16 + lrow;
            short8 af = *(const short8*)(ldsA[cur] + row * 80 + lk * 16);
#pragma unroll
            for (int ni = 0; ni < 4; ++ni)
                acc[mi][ni] = __builtin_amdgcn_mfma_f32_16x16x32_bf16(af, bfr[ni], acc[mi][ni], 0, 0, 0);
        }
        if (s < 7) {
            if ((s & 1) == 0) { WRITEW_(cur ^ 1, wfY); }
            else              { WRITEW_(cur ^ 1, wfX); }
            if (s < 6) asm volatile("s_waitcnt vmcnt(8) lgkmcnt(0)" ::: "memory");  // drain A(s+1); keep W(s+2)
            else       asm volatile("s_waitcnt vmcnt(0) lgkmcnt(0)" ::: "memory");  // last: drain A(7)
            __builtin_amdgcn_s_barrier();
        }
    }

#undef DMA_A
#undef LOADW_
#undef WRITEW_

    // epilogue: loss partials
    float q[4];
#pragma unroll
    for (int ni = 0; ni < 4; ++ni) {
        int dcol = dbase + wn * 64 + ni * 16 + lrow;
        q[ni] = biasL[o * D_ + dcol] + boL[o * D_ + dcol];
    }
    float ssum[4][4];
#pragma unroll
    for (int mi = 0; mi < 4; ++mi)
#pragma unroll
        for (int r = 0; r < 4; ++r) ssum[mi][r] = 0.f;

#pragma unroll
    for (int mi = 0; mi < 4; ++mi) {
#pragma unroll
        for (int ni = 0; ni < 4; ++ni) {
            int dcol = dbase + wn * 64 + ni * 16 + lrow;
#pragma unroll
            for (int r = 0; r < 4; ++r) {
                int rowm = wm * 64 + mi * 16 + lk * 4 + r;
                float tv = acc[mi][ni][r] + rsign * rp[rowm * D_ + dcol] + q[ni];
                ssum[mi][r] += tv * tv;
            }
        }
    }
#pragma unroll
    for (int mi = 0; mi < 4; ++mi)
#pragma unroll
        for (int r = 0; r < 4; ++r) {
            float v = ssum[mi][r];
            v += __shfl_xor(v, 1);
            v += __shfl_xor(v, 2);
            v += __shfl_xor(v, 4);
            v += __shfl_xor(v, 8);
            if (lrow == 0) {
                int rowm = wm * 64 + mi * 16 + lk * 4 + r;
                partial[(rowm * OPT_ + o) * 48 + (bx % 24) * 2 + wn] = v;
            }
        }
}

// ---------------------------------------------------------------------------
// C (R7 verbatim): per-b argmin over 32 options (tie-break lowest index).
__global__ __launch_bounds__(256) void c_kernel(const float* __restrict__ partial,
                                                int* __restrict__ idxbuf,
                                                float* __restrict__ enc, int layer) {
    __shared__ float ls[32];
    int b = blockIdx.x, t = threadIdx.x;
    int oo = t >> 3, j8 = t & 7;
    const float* pp = partial + (b * OPT_ + oo) * 48;
    float v = 0.f;
#pragma unroll
    for (int j = 0; j < 6; ++j) v += pp[j8 + 8 * j];
    v += __shfl_xor(v, 1);
    v += __shfl_xor(v, 2);
    v += __shfl_xor(v, 4);
    if (j8 == 0) ls[oo] = v;
    __syncthreads();
    if (t < 32) {
        float mv = ls[t];
        int mi = t;
#pragma unroll
        for (int m = 16; m >= 1; m >>= 1) {
            float ov = __shfl_xor(mv, m);
            int oi = __shfl_xor(mi, m);
            if (ov < mv || (ov == mv && oi < mi)) { mv = ov; mi = oi; }
        }
        if (t == 0) {
            idxbuf[b] = mi;
            enc[b * NL_ + layer] = (float)mi;
        }
    }
}

// ---------------------------------------------------------------------------
// D: bucketed recompute (R7 core) + FUSED next-layer gemm1 tail.
// grid (32 x 12), 256 threads. After writing cur/rx for its (chunk, d-slice),
// the block re-stages its cur values in LDS (reusing basL) and computes
// zpart2[dt][b][h] = sum_{d in slice} cur[b][d] * Wb[d][h] -- this replaces
// the standalone gemm1 launch (3 launches + ramps removed). Skipped on the
// last layer. Layer 0: cv = 0 (cur was identically 0 -> init eliminated).
__global__ __launch_bounds__(256) void d_kernel(const int* __restrict__ idxbuf,
                                                const float* __restrict__ basef,
                                                const float* __restrict__ Wo,
                                                const float* __restrict__ boL,
                                                const float* __restrict__ biasL,
                                                const float* __restrict__ x,
                                                const float* __restrict__ Wb,
                                                float* __restrict__ cur,
                                                float* __restrict__ rx,
                                                float* __restrict__ zpart2,
                                                int first, int last) {
    __shared__ int sidx[256];
    __shared__ int scnt[32];
    __shared__ int snch[32];
    __shared__ int chunk_b[8];
    __shared__ float basL[8][256];
    int t = threadIdx.x;
    int dt = blockIdx.y;

    sidx[t] = idxbuf[t];
    __syncthreads();
    if (t < 32) {
        int c = 0;
        for (int b = 0; b < 256; ++b) c += (sidx[b] == t);
        scnt[t] = c;
        snch[t] = (c + 7) >> 3;
    }
    __syncthreads();
    int myo = sidx[t];
    int myrank = 0;
    for (int b = 0; b < t; ++b) myrank += (sidx[b] == myo);

    for (int j = blockIdx.x; ; j += 32) {
        int o = -1, ch = 0, pre = 0;
        for (int oo = 0; oo < 32; ++oo) {
            int n = snch[oo];
            if (j < pre + n) { o = oo; ch = j - pre; break; }
            pre += n;
        }
        if (o < 0) break;
        int cnt = scnt[o];
        int c0 = ch * 8;
        int rem = cnt - c0;
        if (rem > 8) rem = 8;

        __syncthreads();   // previous item's basL readers done before reuse
        if (myo == o && myrank >= c0 && myrank < c0 + 8) chunk_b[myrank - c0] = t;
        __syncthreads();

        int bidx[8];
#pragma unroll
        for (int g = 0; g < 8; ++g) bidx[g] = chunk_b[(g < rem) ? g : (rem - 1)];
#pragma unroll
        for (int g = 0; g < 8; ++g) basL[g][t] = basef[bidx[g] * H_ + t];
        __syncthreads();

        int d = dt * 256 + t;
        const float* wp = Wo + (size_t)o * D_ + d;
        size_t nn = (size_t)o * D_ + d;
        float bov = boL[nn];
        float biv = biasL[nn];

        float acc[8] = {0.f, 0.f, 0.f, 0.f, 0.f, 0.f, 0.f, 0.f};
        for (int k0 = 0; k0 < 256; k0 += 8) {
            float w[8];
#pragma unroll
            for (int u = 0; u < 8; ++u) w[u] = wp[(size_t)(k0 + u) * OD_];
#pragma unroll
            for (int h = 0; h < 2; ++h) {
                int kb = k0 + h * 4;
                f32x4 bv[8];
#pragma unroll
                for (int g = 0; g < 8; ++g) bv[g] = *(const f32x4*)&basL[g][kb];
#pragma unroll
                for (int u = 0; u < 4; ++u) {
                    float wu = w[h * 4 + u];
#pragma unroll
                    for (int g = 0; g < 8; ++g) acc[g] += bv[g][u] * wu;   // k ascending
                }
            }
        }
        float fout[8] = {0.f, 0.f, 0.f, 0.f, 0.f, 0.f, 0.f, 0.f};
#pragma unroll
        for (int g = 0; g < 8; ++g) {
            if (g < rem) {
                int b = bidx[g];
                float cv = first ? 0.f : cur[b * D_ + d];
                float outv = cv + acc[g] + bov + biv;
                fout[g] = outv;
                cur[b * D_ + d] = outv;
                rx[b * D_ + d] = outv - x[b * D_ + d];
            }
        }

        // ---- fused gemm1 tail: zpart2[dt][b][h] for next layer's base ----
        if (!last) {
            __syncthreads();                 // k-loop readers of basL done
#pragma unroll
            for (int g = 0; g < 8; ++g) basL[g][t] = fout[g];   // now holds cur slice
            __syncthreads();
            const float* wbp = Wb + (size_t)(dt * 256) * H_ + t;
            float zacc[8] = {0.f, 0.f, 0.f, 0.f, 0.f, 0.f, 0.f, 0.f};
#pragma unroll 4
            for (int dd = 0; dd < 256; ++dd) {
                float w = wbp[(size_t)dd * H_];
#pragma unroll
                for (int g = 0; g < 8; ++g) zacc[g] += basL[g][dd] * w;   // d ascending
            }
#pragma unroll
            for (int g = 0; g < 8; ++g)
                if (g < rem)
                    zpart2[dt * (B_ * H_) + bidx[g] * H_ + t] = zacc[g];
        }
    }
}

// ---------------------------------------------------------------------------
extern "C" void kernel_launch(void* const* d_in, const int* in_sizes, int n_in,
                              void* d_out, int out_size, void* d_ws, size_t ws_size,
                              hipStream_t stream) {
    const float* x    = (const float*)d_in[0];  // [256][3072]
    const float* Wb   = (const float*)d_in[1];  // [3072][256]
    const float* bb   = (const float*)d_in[2];  // [256]
    const float* Wo   = (const float*)d_in[3];  // [4][256][98304]
    const float* bo   = (const float*)d_in[4];  // [4][98304]
    const float* bias = (const float*)d_in[5];  // [4][32][3072]

    float* out = (float*)d_out;
    float* enc = out;            // [256][4] (indices as float)
    float* cur = out + 1024;     // [256][3072] reconstruction

    float* ws = (float*)d_ws;
    float* zpart2  = ws;                          // 12*256*256 = 786432
    float* partial = ws + 786432;                 // 256*32*48  = 393216
    float* rx      = ws + 1179648;                // 256*3072   = 786432
    float* basef   = ws + 1966080;                // 256*256    = 65536
    unsigned char* base_ready = (unsigned char*)(ws + 2031616);  // 163840 B
    int* idxbuf    = (int*)(ws + 2072576);        // 256 ints

    for (int i = 0; i < NL_; ++i) {
        const float* WoL   = Wo + (size_t)i * H_ * OD_;
        const float* boLp  = bo + (size_t)i * OD_;
        const float* biasL = bias + (size_t)i * OD_;
        const float* rp    = (i == 0) ? x : rx;
        float rsign        = (i == 0) ? -1.f : 1.f;
        e_kernel<<<256, 256, 0, stream>>>(zpart2, bb, base_ready, basef, i == 0);
        g2_kernel<<<768, 512, 0, stream>>>(base_ready, WoL, biasL, boLp, rp, rsign, partial);
        c_kernel<<<256, 256, 0, stream>>>(partial, idxbuf, enc, i);
        d_kernel<<<dim3(32, 12), 256, 0, stream>>>(idxbuf, basef, WoL, boLp, biasL, x, Wb,
                                                   cur, rx, zpart2, i == 0, i == NL_ - 1);
    }
}